// Round 5
// baseline (496.807 us; speedup 1.0000x reference)
//
#include <hip/hip_runtime.h>
#include <hip/hip_bf16.h>
#include <stdint.h>

// Problem constants (from reference)
#define M_DIM 8192              // 4*2048 batch*seq rows
#define N_DIM 4096              // out_features
#define K_DIM 4096              // in_features
#define NOG   4096              // num out groups (out_group=1)
#define NIG   512               // num in groups (in_group=8)

typedef __bf16 bf16;
typedef __attribute__((ext_vector_type(8))) __bf16 bf16x8;   // 4 VGPRs — MFMA A/B frag
typedef __attribute__((ext_vector_type(4))) float f32x4;     // MFMA C/D frag

// Tiled bf16 layout ("chunk order") for both GEMM operands:
//   tile(g, h) = rows [g*16,(g+1)*16) x cols [h*32,(h+1)*32)
//   stored as 64 consecutive 16-B chunks, chunk c = kblk*16 + row.
//   tile elem base = (g * 128 + h) * 512.
// GEMM staging reads 1024 CONTIGUOUS bytes per gload16 (lane l -> chunk l)
// and LDS receives fragment-read order -> zero bank conflicts (R4-verified).

// ---------------------------------------------------------------------------
// async global->LDS, 16 B per lane. LDS dest is wave-uniform base + lane*16.
__device__ __forceinline__ void gload16(const void* g, void* lds) {
    __builtin_amdgcn_global_load_lds(
        (__attribute__((address_space(1))) void*)g,
        (__attribute__((address_space(3))) void*)lds,
        16 /*size*/, 0 /*offset*/, 0 /*aux*/);
}

// ---------------------------------------------------------------------------
// Prep kernel (merged): blocks [0,16384) convert the activation fp32->bf16
// into chunk-order tiles; blocks [16384,24576) dequantize W into tiles.
__global__ __launch_bounds__(256) void k_prep(const float* __restrict__ in,
                                              bf16* __restrict__ Abf,
                                              const int* __restrict__ codes,
                                              const float* __restrict__ cb,
                                              const float* __restrict__ scales,
                                              bf16* __restrict__ Wbf) {
    __shared__ __align__(16) bf16 tile[256 * 8];   // 4 KB (convert path only)
    const int t = threadIdx.x;
    const int bid = blockIdx.x;
    if (bid < 16384) {
        // ---- convert: 16 rows x 128 cols (4 tiles) per block ----
        const int g   = bid >> 5;            // row group (512)
        const int h0  = (bid & 31) * 4;      // first 32-col half
        const int row = t >> 4;
        const int cc  = t & 15;              // 8-elem column chunk in 128 cols
        const float4* p = (const float4*)(in + (size_t)(g * 16 + row) * K_DIM
                                             + h0 * 32 + cc * 8);
        float4 a = p[0], b = p[1];
        bf16x8 v;
        v[0] = (bf16)a.x; v[1] = (bf16)a.y; v[2] = (bf16)a.z; v[3] = (bf16)a.w;
        v[4] = (bf16)b.x; v[5] = (bf16)b.y; v[6] = (bf16)b.z; v[7] = (bf16)b.w;
        const int widx = (cc >> 2) * 64 + (cc & 3) * 16 + row;  // chunk order
        ((bf16x8*)tile)[widx] = v;
        __syncthreads();
        bf16x8 o = ((bf16x8*)tile)[t];
        ((bf16x8*)Abf)[((size_t)g * 128 + h0) * 64 + t] = o;    // 4 KB contig
    } else {
        // ---- dequant: 16 out-rows x 16 in-groups (4 tiles) per block ----
        const int b    = bid - 16384;
        const int gB   = b >> 5;             // out-feature group (256)
        const int h0   = (b & 31) * 4;       // first 32-col half
        const int hl   = t >> 6;             // half within block (0..3)
        const int kblk = (t >> 4) & 3;       // in-group within half
        const int row  = t & 15;             // out-feature within group
        const int o    = gB * 16 + row;
        const int iG   = (b & 31) * 16 + hl * 4 + kblk;
        unsigned code = (unsigned)codes[o * NIG + iG];
        float s = scales[o];
        const float4* e = (const float4*)(cb + (size_t)code * 8);
        float4 e0 = e[0], e1 = e[1];
        bf16x8 v;
        v[0] = (bf16)(e0.x * s); v[1] = (bf16)(e0.y * s);
        v[2] = (bf16)(e0.z * s); v[3] = (bf16)(e0.w * s);
        v[4] = (bf16)(e1.x * s); v[5] = (bf16)(e1.y * s);
        v[6] = (bf16)(e1.z * s); v[7] = (bf16)(e1.w * s);
        ((bf16x8*)Wbf)[((size_t)gB * 128 + h0) * 64 + t] = v;
    }
}

// ---------------------------------------------------------------------------
// GEMM: C[m,n] = sum_k A[m,k]*B[n,k] + bias[n]  on chunk-order tiles.
// BM=256 x BN=128 x BK=32, 4 waves (2x2), wave tile 128x64.
// DOUBLE-BUFFERED K-loop, barrier-before-prefetch ordering:
//   barrier (drains loads issued a full iter ago) -> issue loads(ks+1) into
//   buf^1 -> ds_read + MFMA from buf. One barrier/iter; the vmcnt(0) drain
//   at each barrier waits on loads that had ~1 iteration of compute to land.
#define BM 256
#define BN 128
#define BK 32
#define KSTEPS (K_DIM / BK)    // 128

__global__ __launch_bounds__(256, 2) void k_gemm_dbuf(
    const bf16* __restrict__ A,      // chunk-order tiled [512 g][128 h]
    const bf16* __restrict__ B,      // chunk-order tiled [256 g][128 h]
    const float* __restrict__ bias,  // [N_DIM]
    float* __restrict__ C)           // [M_DIM, N_DIM] row-major
{
    __shared__ __align__(16) bf16 As[2][BM * BK];   // 2 x 16 KB
    __shared__ __align__(16) bf16 Bs[2][BN * BK];   // 2 x  8 KB  (48 KB total)

    const int tid  = threadIdx.x;
    const int wave = tid >> 6;         // 0..3
    const int lane = tid & 63;
    const int quad = lane >> 4;        // 0..3
    const int l16  = lane & 15;

    const int bn0 = blockIdx.x * BN;
    const int bm0 = blockIdx.y * BM;
    const int wm = (wave >> 1) * 128;  // wave's 128x64 subtile
    const int wn = (wave & 1) * 64;

    // Staging sources: lane l fetches chunk l of each group-half tile.
    // Wave stages A groups 4w..4w+3, B groups 2w..2w+1; half h = ks.
    const bf16* pA[4];
    const bf16* pB[2];
    #pragma unroll
    for (int gi = 0; gi < 4; ++gi)
        pA[gi] = A + (size_t)(blockIdx.y * 16 + wave * 4 + gi) * (128 * 512)
                   + lane * 8;
    #pragma unroll
    for (int gi = 0; gi < 2; ++gi)
        pB[gi] = B + (size_t)(blockIdx.x * 8 + wave * 2 + gi) * (128 * 512)
                   + lane * 8;

    const int gA0 = (wave >> 1) * 8;   // first A group this wave reads
    const int gB0 = (wave & 1) * 4;    // first B group this wave reads

    f32x4 acc[8][4] = {};

    // Prologue: stage ks=0 into buffer 0.
    {
        bf16* AsW = As[0] + wave * 4 * 512;
        bf16* BsW = Bs[0] + wave * 2 * 512;
        #pragma unroll
        for (int gi = 0; gi < 4; ++gi) gload16(pA[gi], AsW + gi * 512);
        #pragma unroll
        for (int gi = 0; gi < 2; ++gi) gload16(pB[gi], BsW + gi * 512);
    }

    #pragma unroll 2
    for (int ks = 0; ks < KSTEPS; ++ks) {
        __syncthreads();   // drains buf[ks&1] loads (issued one iter ago);
                           // also: all waves done reading buf[(ks+1)&1]

        if (ks + 1 < KSTEPS) {           // prefetch ks+1 into the other buffer
            const int nb = (ks + 1) & 1;
            bf16* AsW = As[nb] + wave * 4 * 512;
            bf16* BsW = Bs[nb] + wave * 2 * 512;
            const size_t off = (size_t)(ks + 1) * 512;
            #pragma unroll
            for (int gi = 0; gi < 4; ++gi) gload16(pA[gi] + off, AsW + gi * 512);
            #pragma unroll
            for (int gi = 0; gi < 2; ++gi) gload16(pB[gi] + off, BsW + gi * 512);
        }

        const bf16* Ab = As[ks & 1];
        const bf16* Bb = Bs[ks & 1];
        bf16x8 af[8], bq[4];
        #pragma unroll
        for (int t = 0; t < 8; ++t)
            af[t] = *(const bf16x8*)(Ab + (size_t)(gA0 + t) * 512 + lane * 8);
        #pragma unroll
        for (int t = 0; t < 4; ++t)
            bq[t] = *(const bf16x8*)(Bb + (size_t)(gB0 + t) * 512 + lane * 8);

        #pragma unroll
        for (int i = 0; i < 8; ++i)
            #pragma unroll
            for (int j = 0; j < 4; ++j)
                acc[i][j] = __builtin_amdgcn_mfma_f32_16x16x32_bf16(
                    af[i], bq[j], acc[i][j], 0, 0, 0);
    }

    // Epilogue: C/D layout col = lane&15, row = quad*4 + reg  [m89/m91-verified]
    #pragma unroll
    for (int j = 0; j < 4; ++j) {
        const int gn = bn0 + wn + j * 16 + l16;
        const float bz = bias[gn];
        #pragma unroll
        for (int i = 0; i < 8; ++i) {
            float* cp = C + (size_t)(bm0 + wm + i * 16 + quad * 4) * N_DIM + gn;
            #pragma unroll
            for (int r = 0; r < 4; ++r)
                cp[(size_t)r * N_DIM] = acc[i][j][r] + bz;
        }
    }
}

// ---------------------------------------------------------------------------
extern "C" void kernel_launch(void* const* d_in, const int* in_sizes, int n_in,
                              void* d_out, int out_size, void* d_ws, size_t ws_size,
                              hipStream_t stream) {
    const float* input     = (const float*)d_in[0];   // [4,2048,4096]
    const int*   codes     = (const int*)d_in[1];     // [4096,512,1]
    const float* codebooks = (const float*)d_in[2];   // [1,65536,1,8]
    const float* scales    = (const float*)d_in[3];   // [4096]
    const float* bias      = (const float*)d_in[4];   // [4096]
    float* out = (float*)d_out;                        // [4,2048,4096]

    // Workspace: A_tiled (67.1 MB) then W_tiled (33.5 MB); both fully written
    // before the GEMM reads them, so the 0xAA poison is irrelevant.
    bf16* Abf = (bf16*)d_ws;
    bf16* Wbf = (bf16*)((char*)d_ws + (size_t)M_DIM * K_DIM * sizeof(bf16));

    (void)in_sizes; (void)n_in; (void)out_size; (void)ws_size;

    // 1+2) convert + dequant, one launch (16384 convert blocks, 8192 dequant)
    k_prep<<<16384 + 8192, 256, 0, stream>>>(input, Abf, codes, codebooks,
                                             scales, Wbf);

    // 3) NT GEMM + bias on tiled operands, double-buffered
    dim3 g(N_DIM / BN, M_DIM / BM);   // (32, 32)
    k_gemm_dbuf<<<g, 256, 0, stream>>>(Abf, Wbf, bias, out);
}